// Round 1
// baseline (214.018 us; speedup 1.0000x reference)
//
#include <hip/hip_runtime.h>
#include <math.h>

#define NQ    12
#define DIM   4096      // 2^NQ
#define BLK   256
#define NPAIR 11        // entangle blocks (6 even pairs + 5 odd pairs)

// XOR swizzle on float2-element index: kills power-of-2-stride bank conflicts
__device__ __forceinline__ int swz(int i) { return i ^ ((i >> 4) & 15); }

__device__ __forceinline__ float2 cmul(float2 a, float2 b) {
    return make_float2(a.x*b.x - a.y*b.y, a.x*b.y + a.y*b.x);
}
__device__ __forceinline__ float2 cadd(float2 a, float2 b) {
    return make_float2(a.x + b.x, a.y + b.y);
}
__device__ __forceinline__ float2 cfma2(float2 a, float2 b, float2 c) {
    c.x = fmaf(a.x, b.x, fmaf(-a.y, b.y, c.x));
    c.y = fmaf(a.x, b.y, fmaf( a.y, b.x, c.y));
    return c;
}

// U = Rz(p2) @ Ry(p1) @ Rz(p0)
// U00 = cb e^{-i(p0+p2)/2}; U01 = -sb e^{i(p0-p2)/2}; U10 = sb e^{-i(p0-p2)/2}; U11 = cb e^{i(p0+p2)/2}
__device__ __forceinline__ void build_su2(const float* __restrict__ p, float2 U[2][2]) {
    float sb, cb;
    sincosf(0.5f * p[1], &sb, &cb);
    float ap = 0.5f * (p[0] + p[2]);
    float am = 0.5f * (p[0] - p[2]);
    float sap, cap, sam, cam;
    sincosf(ap, &sap, &cap);
    sincosf(am, &sam, &cam);
    U[0][0] = make_float2( cb * cap, -cb * sap);
    U[0][1] = make_float2(-sb * cam, -sb * sam);
    U[1][0] = make_float2( sb * cam, -sb * sam);
    U[1][1] = make_float2( cb * cap,  cb * sap);
}

__global__ __launch_bounds__(BLK, 4) void qcnn_kernel(
    const float* __restrict__ x,
    const float* __restrict__ W,
    const float* __restrict__ bias,
    const float* __restrict__ params,
    float* __restrict__ out)
{
    __shared__ float2 st[DIM];              // 32 KB state
    __shared__ float  sgm[NPAIR * 32 + 8];  // 11 entangle 4x4 complex + final 2x2 complex
    __shared__ float  sqf[NQ], sqc[NQ], sqs[NQ], szz[NQ - 1];
    __shared__ float  red[BLK / 64];

    const int tid = threadIdx.x;
    const int b   = blockIdx.x;

    // ---- per-block uniform precompute ----
    if (tid < NQ) {
        float acc = bias[tid];
        const float* xr = x + b * 16;
        const float* wr = W + tid * 16;
        #pragma unroll
        for (int k = 0; k < 16; ++k) acc = fmaf(xr[k], wr[k], acc);
        sqf[tid] = acc;
        float s, c;
        sincosf(0.5f * acc, &s, &c);
        sqc[tid] = c;
        sqs[tid] = s;
    }
    if (tid < NPAIR) {
        // compose U = (A2 kron B2) @ ZZ @ YY @ XX @ (A1 kron B1)   (4x4 complex)
        const float* pp = params + 15 * tid;
        float2 A1[2][2], B1[2][2], A2[2][2], B2[2][2];
        build_su2(pp + 0,  A1);
        build_su2(pp + 3,  B1);
        build_su2(pp + 9,  A2);
        build_su2(pp + 12, B2);
        float thx = pp[6], thy = pp[7], thz = pp[8];
        float Sa, Ca, Sb, Cb, sz, cz;
        sincosf(0.5f * (thx - thy), &Sa, &Ca);   // {00,11} subspace rotation
        sincosf(0.5f * (thx + thy), &Sb, &Cb);   // {01,10} subspace rotation
        sincosf(0.5f * thz, &sz, &cz);
        float2 pz  = make_float2(cz, -sz);       // e^{-i thz/2} (bits equal)
        float2 pzc = make_float2(cz,  sz);       // e^{+i thz/2} (bits differ)
        float2 K00 = make_float2(Ca * pz.x,  Ca * pz.y);
        float2 K03 = cmul(make_float2(0.f, -Sa), pz);
        float2 K11 = make_float2(Cb * pzc.x, Cb * pzc.y);
        float2 K12 = cmul(make_float2(0.f, -Sb), pzc);

        float2 T0[4][4], M1[4][4], T2[4][4];
        #pragma unroll
        for (int i = 0; i < 2; ++i)
            #pragma unroll
            for (int jj = 0; jj < 2; ++jj)
                #pragma unroll
                for (int k = 0; k < 2; ++k)
                    #pragma unroll
                    for (int l = 0; l < 2; ++l) {
                        T0[2*i+jj][2*k+l] = cmul(A1[i][k], B1[jj][l]);
                        T2[2*i+jj][2*k+l] = cmul(A2[i][k], B2[jj][l]);
                    }
        #pragma unroll
        for (int c = 0; c < 4; ++c) {
            M1[0][c] = cadd(cmul(K00, T0[0][c]), cmul(K03, T0[3][c]));
            M1[1][c] = cadd(cmul(K11, T0[1][c]), cmul(K12, T0[2][c]));
            M1[2][c] = cadd(cmul(K12, T0[1][c]), cmul(K11, T0[2][c]));
            M1[3][c] = cadd(cmul(K03, T0[0][c]), cmul(K00, T0[3][c]));
        }
        #pragma unroll
        for (int r = 0; r < 4; ++r)
            #pragma unroll
            for (int c = 0; c < 4; ++c) {
                float2 a = make_float2(0.f, 0.f);
                #pragma unroll
                for (int k = 0; k < 4; ++k) a = cfma2(T2[r][k], M1[k][c], a);
                sgm[tid * 32 + (r * 4 + c) * 2]     = a.x;
                sgm[tid * 32 + (r * 4 + c) * 2 + 1] = a.y;
            }
    }
    if (tid == 16) {   // final SU2 on wire 0
        float2 F[2][2];
        build_su2(params + 15 * NPAIR, F);
        sgm[352] = F[0][0].x; sgm[353] = F[0][0].y;
        sgm[354] = F[0][1].x; sgm[355] = F[0][1].y;
        sgm[356] = F[1][0].x; sgm[357] = F[1][0].y;
        sgm[358] = F[1][1].x; sgm[359] = F[1][1].y;
    }
    __syncthreads();
    if (tid < NQ - 1) szz[tid] = sqf[tid] * sqf[tid + 1];
    __syncthreads();

    // ---- init pass: layer-1 RYs on |0..0> (product state) + layer-1 ZZ diagonal ----
    for (int idx = tid; idx < DIM; idx += BLK) {
        float amp = 1.f;
        #pragma unroll
        for (int q = 0; q < NQ; ++q) {
            int m = (idx >> (11 - q)) & 1;
            amp *= m ? sqs[q] : sqc[q];
        }
        float ang = 0.f;
        #pragma unroll
        for (int q = 0; q < NQ - 1; ++q) {
            int d = ((idx >> (11 - q)) ^ (idx >> (10 - q))) & 1;
            ang += d ? -szz[q] : szz[q];
        }
        ang *= 0.5f;
        float sa, ca;
        sincosf(ang, &sa, &ca);
        st[swz(idx)] = make_float2(amp * ca, -amp * sa);   // amp * e^{-i ang}
    }
    __syncthreads();

    // ---- layer 2: 6 fused RY(x)RY passes on wire pairs (0,1)..(10,11) ----
    #pragma unroll 1
    for (int pr = 0; pr < 6; ++pr) {
        int wa = 2 * pr;
        int pb = 10 - wa;                 // bit of wire wa+1; bit of wa is pb+1
        float ca = sqc[wa],     sa = sqs[wa];
        float cb = sqc[wa + 1], sb = sqs[wa + 1];
        #pragma unroll
        for (int g = tid; g < DIM / 4; g += BLK) {
            int low = g & ((1 << pb) - 1);
            int i00 = low | ((g >> pb) << (pb + 2));
            int i01 = i00 | (1 << pb);
            int i10 = i00 | (2 << pb);
            int i11 = i10 | (1 << pb);
            float2 a00 = st[swz(i00)], a01 = st[swz(i01)];
            float2 a10 = st[swz(i10)], a11 = st[swz(i11)];
            // RY on wire a: pairs (a00,a10), (a01,a11)
            float2 t00 = make_float2(ca*a00.x - sa*a10.x, ca*a00.y - sa*a10.y);
            float2 t10 = make_float2(sa*a00.x + ca*a10.x, sa*a00.y + ca*a10.y);
            float2 t01 = make_float2(ca*a01.x - sa*a11.x, ca*a01.y - sa*a11.y);
            float2 t11 = make_float2(sa*a01.x + ca*a11.x, sa*a01.y + ca*a11.y);
            // RY on wire b: pairs (t00,t01), (t10,t11)
            st[swz(i00)] = make_float2(cb*t00.x - sb*t01.x, cb*t00.y - sb*t01.y);
            st[swz(i01)] = make_float2(sb*t00.x + cb*t01.x, sb*t00.y + cb*t01.y);
            st[swz(i10)] = make_float2(cb*t10.x - sb*t11.x, cb*t10.y - sb*t11.y);
            st[swz(i11)] = make_float2(sb*t10.x + cb*t11.x, sb*t10.y + cb*t11.y);
        }
        __syncthreads();
    }

    // ---- layer 2: fused ZZ diagonal ----
    for (int idx = tid; idx < DIM; idx += BLK) {
        float ang = 0.f;
        #pragma unroll
        for (int q = 0; q < NQ - 1; ++q) {
            int d = ((idx >> (11 - q)) ^ (idx >> (10 - q))) & 1;
            ang += d ? -szz[q] : szz[q];
        }
        ang *= 0.5f;
        float sa, ca;
        sincosf(ang, &sa, &ca);
        int l = swz(idx);
        st[l] = cmul(st[l], make_float2(ca, -sa));
    }
    __syncthreads();

    // ---- 11 entangle passes: one composed 4x4 per adjacent wire pair ----
    #pragma unroll 1
    for (int e = 0; e < NPAIR; ++e) {
        int wa = (e < 6) ? 2 * e : 2 * (e - 6) + 1;
        int pb = 10 - wa;
        float2 U[4][4];
        #pragma unroll
        for (int r = 0; r < 4; ++r)
            #pragma unroll
            for (int c = 0; c < 4; ++c)
                U[r][c] = make_float2(sgm[e*32 + (r*4+c)*2], sgm[e*32 + (r*4+c)*2 + 1]);
        #pragma unroll
        for (int g = tid; g < DIM / 4; g += BLK) {
            int low = g & ((1 << pb) - 1);
            int i00 = low | ((g >> pb) << (pb + 2));
            int i01 = i00 | (1 << pb);
            int i10 = i00 | (2 << pb);
            int i11 = i10 | (1 << pb);
            // 4-vector index = 2*bit_a + bit_b
            float2 a0 = st[swz(i00)], a1 = st[swz(i01)];
            float2 a2 = st[swz(i10)], a3 = st[swz(i11)];
            float2 r0 = cmul(U[0][0], a0); r0 = cfma2(U[0][1], a1, r0); r0 = cfma2(U[0][2], a2, r0); r0 = cfma2(U[0][3], a3, r0);
            float2 r1 = cmul(U[1][0], a0); r1 = cfma2(U[1][1], a1, r1); r1 = cfma2(U[1][2], a2, r1); r1 = cfma2(U[1][3], a3, r1);
            float2 r2 = cmul(U[2][0], a0); r2 = cfma2(U[2][1], a1, r2); r2 = cfma2(U[2][2], a2, r2); r2 = cfma2(U[2][3], a3, r2);
            float2 r3 = cmul(U[3][0], a0); r3 = cfma2(U[3][1], a1, r3); r3 = cfma2(U[3][2], a2, r3); r3 = cfma2(U[3][3], a3, r3);
            st[swz(i00)] = r0; st[swz(i01)] = r1;
            st[swz(i10)] = r2; st[swz(i11)] = r3;
        }
        __syncthreads();
    }

    // ---- final SU2 on wire 0 fused into probability reduction ----
    float2 F00 = make_float2(sgm[352], sgm[353]);
    float2 F01 = make_float2(sgm[354], sgm[355]);
    float2 F10 = make_float2(sgm[356], sgm[357]);
    float2 F11 = make_float2(sgm[358], sgm[359]);
    float acc = 0.f;
    for (int i = tid; i < DIM / 2; i += BLK) {
        float2 a0 = st[swz(i)];
        float2 a1 = st[swz(i + DIM / 2)];
        float2 n0 = cfma2(F01, a1, cmul(F00, a0));
        float2 n1 = cfma2(F11, a1, cmul(F10, a0));
        acc += n0.x*n0.x + n0.y*n0.y - n1.x*n1.x - n1.y*n1.y;
    }
    #pragma unroll
    for (int off = 32; off > 0; off >>= 1) acc += __shfl_down(acc, off);
    if ((tid & 63) == 0) red[tid >> 6] = acc;
    __syncthreads();
    if (tid == 0) {
        float d = red[0] + red[1] + red[2] + red[3];
        float y = 0.5f * (d + 1.0f);
        y = fminf(fmaxf(y, 1e-6f), 1.0f - 1e-6f);
        out[b] = y;
    }
}

extern "C" void kernel_launch(void* const* d_in, const int* in_sizes, int n_in,
                              void* d_out, int out_size, void* d_ws, size_t ws_size,
                              hipStream_t stream) {
    (void)in_sizes; (void)n_in; (void)d_ws; (void)ws_size;
    const float* x      = (const float*)d_in[0];
    const float* W      = (const float*)d_in[1];
    const float* bias   = (const float*)d_in[2];
    const float* params = (const float*)d_in[3];
    float* out = (float*)d_out;
    hipLaunchKernelGGL(qcnn_kernel, dim3(out_size), dim3(BLK), 0, stream,
                       x, W, bias, params, out);
}

// Round 2
// 138.621 us; speedup vs baseline: 1.5439x; 1.5439x over previous
//
#include <hip/hip_runtime.h>
#include <math.h>

#define NQ  12
#define DIM 4096
#define BLK 256

// XOR swizzle on float2 index: conflict-free for all pass access patterns
__device__ __forceinline__ int S(int i) { return i ^ ((i >> 4) & 15); }

__device__ __forceinline__ float2 cmul(float2 a, float2 b) {
    return make_float2(a.x*b.x - a.y*b.y, a.x*b.y + a.y*b.x);
}
__device__ __forceinline__ float2 cadd(float2 a, float2 b) {
    return make_float2(a.x + b.x, a.y + b.y);
}
__device__ __forceinline__ float2 cfma2(float2 a, float2 b, float2 c) {
    c.x = fmaf(a.x, b.x, fmaf(-a.y, b.y, c.x));
    c.y = fmaf(a.x, b.y, fmaf( a.y, b.x, c.y));
    return c;
}
// e^{-i*th/2 * (d ? -1 : +1)}
__device__ __forceinline__ float2 phfac(float ch, float sh, int d) {
    return make_float2(ch, d ? sh : -sh);
}

// U = Rz(p2) @ Ry(p1) @ Rz(p0)
__device__ __forceinline__ void build_su2(const float* __restrict__ p, float2 U[2][2]) {
    float sb, cb;
    sincosf(0.5f * p[1], &sb, &cb);
    float ap = 0.5f * (p[0] + p[2]);
    float am = 0.5f * (p[0] - p[2]);
    float sap, cap, sam, cam;
    sincosf(ap, &sap, &cap);
    sincosf(am, &sam, &cam);
    U[0][0] = make_float2( cb * cap, -cb * sap);
    U[0][1] = make_float2(-sb * cam, -sb * sam);
    U[1][0] = make_float2( sb * cam, -sb * sam);
    U[1][1] = make_float2( cb * cap,  cb * sap);
}

// RY on local bit `bit` of a 16-amp register block
__device__ __forceinline__ void ry16(float2* a, int bit, float c, float s) {
    #pragma unroll
    for (int l = 0; l < 16; ++l)
        if ((l & bit) == 0) {
            float2 lo = a[l], hi = a[l | bit];
            a[l]       = make_float2(fmaf(c, lo.x, -s * hi.x), fmaf(c, lo.y, -s * hi.y));
            a[l | bit] = make_float2(fmaf(s, lo.x,  c * hi.x), fmaf(s, lo.y,  c * hi.y));
        }
}

__device__ __forceinline__ void mload(float2* M, const float2* __restrict__ src) {
    #pragma unroll
    for (int e = 0; e < 16; ++e) M[e] = src[e];
}
// 4x4 gate on local bits (3,2); group g = l&3 fixed
__device__ __forceinline__ void gtop2(float2* a, const float2* M, int g) {
    float2 x0 = a[g], x1 = a[4 | g], x2 = a[8 | g], x3 = a[12 | g];
    #pragma unroll
    for (int r = 0; r < 4; ++r) {
        float2 y = cmul(M[4*r], x0);
        y = cfma2(M[4*r+1], x1, y);
        y = cfma2(M[4*r+2], x2, y);
        y = cfma2(M[4*r+3], x3, y);
        a[4*r | g] = y;
    }
}
// 4x4 gate on local bits (1,0); group q = l>>2 fixed
__device__ __forceinline__ void glow2(float2* a, const float2* M, int q) {
    int b = q << 2;
    float2 x0 = a[b], x1 = a[b|1], x2 = a[b|2], x3 = a[b|3];
    float2 y0 = cmul(M[0], x0);  y0 = cfma2(M[1], x1, y0);  y0 = cfma2(M[2], x2, y0);  y0 = cfma2(M[3], x3, y0);
    float2 y1 = cmul(M[4], x0);  y1 = cfma2(M[5], x1, y1);  y1 = cfma2(M[6], x2, y1);  y1 = cfma2(M[7], x3, y1);
    float2 y2 = cmul(M[8], x0);  y2 = cfma2(M[9], x1, y2);  y2 = cfma2(M[10], x2, y2); y2 = cfma2(M[11], x3, y2);
    float2 y3 = cmul(M[12], x0); y3 = cfma2(M[13], x1, y3); y3 = cfma2(M[14], x2, y3); y3 = cfma2(M[15], x3, y3);
    a[b] = y0; a[b|1] = y1; a[b|2] = y2; a[b|3] = y3;
}

// Matrix slots:
// 0,1: E01[v2]   2,3: E23[v4]   4,5: E45[v6]   6: E67   7: E10_11
// 8..11: E89[v7][v10] = 8+2*v7+v10
// 12: E12  13: E34  14: E56  15: E78  16: E9_10
#define NSLOT 17

__global__ __launch_bounds__(BLK, 3) void qcnn_kernel(
    const float* __restrict__ x,
    const float* __restrict__ W,
    const float* __restrict__ bias,
    const float* __restrict__ params,
    float* __restrict__ out)
{
    __shared__ float2 st[DIM];                 // 32 KB state
    __shared__ float2 sE[NSLOT * 16];          // gate matrices
    __shared__ float2 sF[4];                   // final SU2
    __shared__ float2 sZp[5], sZm[5];          // e^{-+ i szz[3..7]/2}
    __shared__ float  sqf[NQ], sqc[NQ], sqs[NQ], szz[NQ - 1];
    __shared__ float  red[BLK / 64];

    const int tid = threadIdx.x;
    const int b   = blockIdx.x;

    // ---- qfeat ----
    if (tid < NQ) {
        float acc = bias[tid];
        const float* xr = x + b * 16;
        const float* wr = W + tid * 16;
        #pragma unroll
        for (int k = 0; k < 16; ++k) acc = fmaf(xr[k], wr[k], acc);
        sqf[tid] = acc;
        float s, c;
        sincosf(0.5f * acc, &s, &c);
        sqc[tid] = c;
        sqs[tid] = s;
    }
    __syncthreads();

    // ---- setup: szz, Z tables, entangle matrices (+ZZ-folded variants), final SU2 ----
    if (tid < NQ - 1) szz[tid] = sqf[tid] * sqf[tid + 1];
    if (tid < 5) {   // Z tables for pairs q=3..7 (init-pass boundary/local phases)
        float th = sqf[3 + tid] * sqf[4 + tid];
        float sh, ch; sincosf(0.5f * th, &sh, &ch);
        sZp[tid] = make_float2(ch, -sh);   // equal bits
        sZm[tid] = make_float2(ch,  sh);   // differing bits
    }
    if (tid < 11) {
        const float* pp = params + 15 * tid;
        float2 A1[2][2], B1[2][2], A2[2][2], B2[2][2];
        build_su2(pp + 0,  A1);
        build_su2(pp + 3,  B1);
        build_su2(pp + 9,  A2);
        build_su2(pp + 12, B2);
        float thx = pp[6], thy = pp[7], thz = pp[8];
        float Sa, Ca, Sb, Cb, sz, cz;
        sincosf(0.5f * (thx - thy), &Sa, &Ca);
        sincosf(0.5f * (thx + thy), &Sb, &Cb);
        sincosf(0.5f * thz, &sz, &cz);
        float2 pz  = make_float2(cz, -sz);
        float2 pzc = make_float2(cz,  sz);
        float2 K00 = make_float2(Ca * pz.x,  Ca * pz.y);
        float2 K03 = cmul(make_float2(0.f, -Sa), pz);
        float2 K11 = make_float2(Cb * pzc.x, Cb * pzc.y);
        float2 K12 = cmul(make_float2(0.f, -Sb), pzc);

        float2 T0[4][4], M1[4][4], G[4][4];
        #pragma unroll
        for (int i = 0; i < 2; ++i)
            #pragma unroll
            for (int jj = 0; jj < 2; ++jj)
                #pragma unroll
                for (int k = 0; k < 2; ++k)
                    #pragma unroll
                    for (int l = 0; l < 2; ++l) {
                        T0[2*i+jj][2*k+l] = cmul(A1[i][k], B1[jj][l]);
                        G [2*i+jj][2*k+l] = cmul(A2[i][k], B2[jj][l]);  // reuse G as T2
                    }
        #pragma unroll
        for (int c = 0; c < 4; ++c) {
            M1[0][c] = cadd(cmul(K00, T0[0][c]), cmul(K03, T0[3][c]));
            M1[1][c] = cadd(cmul(K11, T0[1][c]), cmul(K12, T0[2][c]));
            M1[2][c] = cadd(cmul(K12, T0[1][c]), cmul(K11, T0[2][c]));
            M1[3][c] = cadd(cmul(K03, T0[0][c]), cmul(K00, T0[3][c]));
        }
        float2 F[4][4];
        #pragma unroll
        for (int r = 0; r < 4; ++r)
            #pragma unroll
            for (int c = 0; c < 4; ++c) {
                float2 acc2 = make_float2(0.f, 0.f);
                #pragma unroll
                for (int k = 0; k < 4; ++k) acc2 = cfma2(G[r][k], M1[k][c], acc2);
                F[r][c] = acc2;
            }

        if (tid < 6) {
            // fold D_{2k,2k+1}: column scale by pa(c), d = va^vb
            float tha = sqf[2*tid] * sqf[2*tid+1];
            float sha, cha; sincosf(0.5f * tha, &sha, &cha);
            if (tid < 3) {            // E01,E23,E45: 2 variants by neighbor bit vn
                float thn = sqf[2*tid+1] * sqf[2*tid+2];
                float shn, chn; sincosf(0.5f * thn, &shn, &chn);
                #pragma unroll
                for (int vn = 0; vn < 2; ++vn)
                    for (int c = 0; c < 4; ++c) {
                        float2 f = cmul(phfac(cha, sha, ((c>>1)^c)&1),
                                        phfac(chn, shn, (c&1)^vn));
                        for (int r = 0; r < 4; ++r)
                            sE[(2*tid+vn)*16 + r*4 + c] = cmul(F[r][c], f);
                    }
            } else if (tid == 3) {    // E67: D67 only
                for (int c = 0; c < 4; ++c) {
                    float2 f = phfac(cha, sha, ((c>>1)^c)&1);
                    for (int r = 0; r < 4; ++r)
                        sE[6*16 + r*4 + c] = cmul(F[r][c], f);
                }
            } else if (tid == 4) {    // E89: D89 + D9_10(v10) + D78(v7): 4 variants
                float thn = sqf[9] * sqf[10];
                float thp = sqf[7] * sqf[8];
                float shn, chn, shp, chp;
                sincosf(0.5f * thn, &shn, &chn);
                sincosf(0.5f * thp, &shp, &chp);
                for (int vp = 0; vp < 2; ++vp)
                    for (int vn = 0; vn < 2; ++vn)
                        for (int c = 0; c < 4; ++c) {
                            float2 f = cmul(phfac(cha, sha, ((c>>1)^c)&1),
                                            phfac(chn, shn, (c&1)^vn));
                            f = cmul(f, phfac(chp, shp, ((c>>1)&1)^vp));
                            for (int r = 0; r < 4; ++r)
                                sE[(8+2*vp+vn)*16 + r*4 + c] = cmul(F[r][c], f);
                        }
            } else {                  // tid==5: E10_11: D10_11 only
                for (int c = 0; c < 4; ++c) {
                    float2 f = phfac(cha, sha, ((c>>1)^c)&1);
                    for (int r = 0; r < 4; ++r)
                        sE[7*16 + r*4 + c] = cmul(F[r][c], f);
                }
            }
        } else {                      // odd blocks E12,E34,E56,E78,E9_10: slots 12..16
            for (int r = 0; r < 4; ++r)
                for (int c = 0; c < 4; ++c)
                    sE[(12 + tid - 6)*16 + r*4 + c] = F[r][c];
        }
    }
    if (tid == 11) {
        float2 Fs[2][2];
        build_su2(params + 165, Fs);
        sF[0] = Fs[0][0]; sF[1] = Fs[0][1]; sF[2] = Fs[1][0]; sF[3] = Fs[1][1];
    }
    __syncthreads();

    // ================= P0: init (L1 product + L1 ZZ phase) + RY4-7, bits 7..4 =====
    {
        const int tH = tid >> 4, tL = tid & 15;
        float A = (tH & 8 ? sqs[0] : sqc[0]) * (tH & 4 ? sqs[1] : sqc[1])
                * (tH & 2 ? sqs[2] : sqc[2]) * (tH & 1 ? sqs[3] : sqc[3]);
        float C = (tL & 8 ? sqs[8] : sqc[8]) * (tL & 4 ? sqs[9] : sqc[9])
                * (tL & 2 ? sqs[10] : sqc[10]) * (tL & 1 ? sqs[11] : sqc[11]);
        float ang = 0.f;
        ang += (((tH>>3) ^ (tH>>2)) & 1) ? -szz[0] : szz[0];
        ang += (((tH>>2) ^ (tH>>1)) & 1) ? -szz[1] : szz[1];
        ang += (((tH>>1) ^  tH)     & 1) ? -szz[2] : szz[2];
        ang += (((tL>>3) ^ (tL>>2)) & 1) ? -szz[8] : szz[8];
        ang += (((tL>>2) ^ (tL>>1)) & 1) ? -szz[9] : szz[9];
        ang += (((tL>>1) ^  tL)     & 1) ? -szz[10] : szz[10];
        float sa, ca; sincosf(0.5f * ang, &sa, &ca);
        float AC = A * C;
        float2 pre = make_float2(AC * ca, -AC * sa);

        const int b3 = tH & 1;        // wire3 bit
        const int b8 = (tL >> 3) & 1; // wire8 bit
        float2 F1[4], F2[4];
        #pragma unroll
        for (int h = 0; h < 4; ++h) {
            int v4_ = h >> 1, v5_ = h & 1;
            float B1 = (v4_ ? sqs[4] : sqc[4]) * (v5_ ? sqs[5] : sqc[5]);
            float2 f = cmul((b3 ^ v4_) ? sZm[0] : sZp[0],
                            (v4_ ^ v5_) ? sZm[1] : sZp[1]);
            f = cmul(pre, f);
            F1[h] = make_float2(B1 * f.x, B1 * f.y);
        }
        #pragma unroll
        for (int h = 0; h < 4; ++h) {
            int v6_ = h >> 1, v7_ = h & 1;
            float B2 = (v6_ ? sqs[6] : sqc[6]) * (v7_ ? sqs[7] : sqc[7]);
            float2 f = cmul((v6_ ^ v7_) ? sZm[3] : sZp[3],
                            (v7_ ^ b8)  ? sZm[4] : sZp[4]);
            F2[h] = make_float2(B2 * f.x, B2 * f.y);
        }
        float2 a[16];
        #pragma unroll
        for (int c = 0; c < 16; ++c) {
            int v5_ = (c >> 2) & 1, v6_ = (c >> 1) & 1;
            float2 z5 = (v5_ ^ v6_) ? sZm[2] : sZp[2];
            a[c] = cmul(cmul(F1[c >> 2], z5), F2[c & 3]);
        }
        ry16(a, 8, sqc[4], sqs[4]);
        ry16(a, 4, sqc[5], sqs[5]);
        ry16(a, 2, sqc[6], sqs[6]);
        ry16(a, 1, sqc[7], sqs[7]);
        const int base = (tH << 8) | tL;
        #pragma unroll
        for (int c = 0; c < 16; ++c) st[S(base | (c << 4))] = a[c];
    }
    __syncthreads();

    // ================= P1: RY8-11 + E89[v7][v10] + E10_11, bits 3..0 =============
    {
        const int base = tid << 4;
        float2 a[16];
        #pragma unroll
        for (int c = 0; c < 16; ++c) a[c] = st[S(base | c)];
        ry16(a, 8, sqc[8],  sqs[8]);
        ry16(a, 4, sqc[9],  sqs[9]);
        ry16(a, 2, sqc[10], sqs[10]);
        ry16(a, 1, sqc[11], sqs[11]);
        const int vp = tid & 1;       // wire7 bit (global bit 4)
        float2 M[16];
        mload(M, sE + (8 + 2*vp) * 16);     gtop2(a, M, 0); gtop2(a, M, 1);
        mload(M, sE + (8 + 2*vp + 1) * 16); gtop2(a, M, 2); gtop2(a, M, 3);
        mload(M, sE + 7 * 16);
        glow2(a, M, 0); glow2(a, M, 1); glow2(a, M, 2); glow2(a, M, 3);
        #pragma unroll
        for (int c = 0; c < 16; ++c) st[S(base | c)] = a[c];
    }
    __syncthreads();

    // ================= P2: RY0-3 + E01[v2] + E23[v4], bits 11..8 =================
    {
        float2 a[16];
        #pragma unroll
        for (int c = 0; c < 16; ++c) a[c] = st[S((c << 8) | tid)];
        ry16(a, 8, sqc[0], sqs[0]);
        ry16(a, 4, sqc[1], sqs[1]);
        ry16(a, 2, sqc[2], sqs[2]);
        ry16(a, 1, sqc[3], sqs[3]);
        float2 M[16];
        mload(M, sE + 0 * 16); gtop2(a, M, 0); gtop2(a, M, 1);
        mload(M, sE + 1 * 16); gtop2(a, M, 2); gtop2(a, M, 3);
        const int v4 = (tid >> 7) & 1;   // wire4 bit (global bit 7)
        mload(M, sE + (2 + v4) * 16);
        glow2(a, M, 0); glow2(a, M, 1); glow2(a, M, 2); glow2(a, M, 3);
        #pragma unroll
        for (int c = 0; c < 16; ++c) st[S((c << 8) | tid)] = a[c];
    }
    __syncthreads();

    // ================= P3: E45[v6] + E67, bits 7..4 ==============================
    {
        const int base = ((tid >> 4) << 8) | (tid & 15);
        float2 a[16];
        #pragma unroll
        for (int c = 0; c < 16; ++c) a[c] = st[S(base | (c << 4))];
        float2 M[16];
        mload(M, sE + 4 * 16); gtop2(a, M, 0); gtop2(a, M, 1);
        mload(M, sE + 5 * 16); gtop2(a, M, 2); gtop2(a, M, 3);
        mload(M, sE + 6 * 16);
        glow2(a, M, 0); glow2(a, M, 1); glow2(a, M, 2); glow2(a, M, 3);
        #pragma unroll
        for (int c = 0; c < 16; ++c) st[S(base | (c << 4))] = a[c];
    }
    __syncthreads();

    // ================= P4: E12 + E34, bits 10..7 =================================
    {
        const int base = ((tid & 128) << 4) | (tid & 127);
        float2 a[16];
        #pragma unroll
        for (int c = 0; c < 16; ++c) a[c] = st[S(base | (c << 7))];
        float2 M[16];
        mload(M, sE + 12 * 16); gtop2(a, M, 0); gtop2(a, M, 1); gtop2(a, M, 2); gtop2(a, M, 3);
        mload(M, sE + 13 * 16);
        glow2(a, M, 0); glow2(a, M, 1); glow2(a, M, 2); glow2(a, M, 3);
        #pragma unroll
        for (int c = 0; c < 16; ++c) st[S(base | (c << 7))] = a[c];
    }
    __syncthreads();

    // ================= P5: E56 + E78, bits 6..3 ==================================
    {
        const int base = ((tid >> 3) << 7) | (tid & 7);
        float2 a[16];
        #pragma unroll
        for (int c = 0; c < 16; ++c) a[c] = st[S(base | (c << 3))];
        float2 M[16];
        mload(M, sE + 14 * 16); gtop2(a, M, 0); gtop2(a, M, 1); gtop2(a, M, 2); gtop2(a, M, 3);
        mload(M, sE + 15 * 16);
        glow2(a, M, 0); glow2(a, M, 1); glow2(a, M, 2); glow2(a, M, 3);
        #pragma unroll
        for (int c = 0; c < 16; ++c) st[S(base | (c << 3))] = a[c];
    }
    __syncthreads();

    // ================= P6: E9_10 + final SU2(wire0) + reduce, bits {11,2,1,0} ====
    {
        const int base = tid << 3;
        float2 a[16];
        #pragma unroll
        for (int c = 0; c < 16; ++c)
            a[c] = st[S(((c & 8) << 8) | base | (c & 7))];
        // E9_10 on local bits (2,1); groups (l3, l0)
        float2 M[16];
        mload(M, sE + 16 * 16);
        #pragma unroll
        for (int g = 0; g < 4; ++g) {
            const int bb = ((g >> 1) << 3) | (g & 1);
            float2 x0 = a[bb], x1 = a[bb + 2], x2 = a[bb + 4], x3 = a[bb + 6];
            #pragma unroll
            for (int r = 0; r < 4; ++r) {
                float2 y = cmul(M[4*r], x0);
                y = cfma2(M[4*r+1], x1, y);
                y = cfma2(M[4*r+2], x2, y);
                y = cfma2(M[4*r+3], x3, y);
                a[bb + 2*r] = y;
            }
        }
        // final SU2 on wire0 (local bit 3) fused with probability
        const float2 F00 = sF[0], F01 = sF[1], F10 = sF[2], F11 = sF[3];
        float acc = 0.f;
        #pragma unroll
        for (int l = 0; l < 8; ++l) {
            float2 lo = a[l], hi = a[l + 8];
            float2 n0 = cfma2(F01, hi, cmul(F00, lo));
            float2 n1 = cfma2(F11, hi, cmul(F10, lo));
            acc += n0.x*n0.x + n0.y*n0.y - (n1.x*n1.x + n1.y*n1.y);
        }
        #pragma unroll
        for (int off = 32; off > 0; off >>= 1) acc += __shfl_down(acc, off);
        if ((tid & 63) == 0) red[tid >> 6] = acc;
        __syncthreads();
        if (tid == 0) {
            float d = red[0] + red[1] + red[2] + red[3];
            float y = 0.5f * (d + 1.0f);
            y = fminf(fmaxf(y, 1e-6f), 1.0f - 1e-6f);
            out[b] = y;
        }
    }
}

extern "C" void kernel_launch(void* const* d_in, const int* in_sizes, int n_in,
                              void* d_out, int out_size, void* d_ws, size_t ws_size,
                              hipStream_t stream) {
    (void)in_sizes; (void)n_in; (void)d_ws; (void)ws_size;
    const float* x      = (const float*)d_in[0];
    const float* W      = (const float*)d_in[1];
    const float* bias   = (const float*)d_in[2];
    const float* params = (const float*)d_in[3];
    float* out = (float*)d_out;
    hipLaunchKernelGGL(qcnn_kernel, dim3(out_size), dim3(BLK), 0, stream,
                       x, W, bias, params, out);
}

// Round 3
// 100.720 us; speedup vs baseline: 2.1249x; 1.3763x over previous
//
#include <hip/hip_runtime.h>
#include <math.h>

#define NQ  12
#define DIM 4096
#define TPB 128

typedef float v2 __attribute__((ext_vector_type(2)));
typedef float v4 __attribute__((ext_vector_type(4)));

__device__ __forceinline__ v2 pfma(v2 a, v2 b, v2 c) { return __builtin_elementwise_fma(a, b, c); }

__device__ __forceinline__ float2 cmul(float2 a, float2 b) {
    return make_float2(a.x*b.x - a.y*b.y, a.x*b.y + a.y*b.x);
}
__device__ __forceinline__ float2 cadd(float2 a, float2 b) {
    return make_float2(a.x + b.x, a.y + b.y);
}
__device__ __forceinline__ float2 cfma2(float2 a, float2 b, float2 c) {
    c.x = fmaf(a.x, b.x, fmaf(-a.y, b.y, c.x));
    c.y = fmaf(a.x, b.y, fmaf( a.y, b.x, c.y));
    return c;
}

// U = Rz(p2) @ Ry(p1) @ Rz(p0)
__device__ __forceinline__ void build_su2(const float* __restrict__ p, float2 U[2][2]) {
    float sb, cb;
    sincosf(0.5f * p[1], &sb, &cb);
    float ap = 0.5f * (p[0] + p[2]);
    float am = 0.5f * (p[0] - p[2]);
    float sap, cap, sam, cam;
    sincosf(ap, &sap, &cap);
    sincosf(am, &sam, &cam);
    U[0][0] = make_float2( cb * cap, -cb * sap);
    U[0][1] = make_float2(-sb * cam, -sb * sam);
    U[1][0] = make_float2( sb * cam, -sb * sam);
    U[1][1] = make_float2( cb * cap,  cb * sap);
}

// ---------- one-time setup kernel: compose the 11 entangle 4x4s + final SU2 ----------
// gm layout: slot e in [0,11): 16 x v4 (re,re,im,im); final F at gm[176..179]
__global__ void qcnn_setup(const float* __restrict__ params, v4* __restrict__ gm) {
    int tid = threadIdx.x;
    if (tid < 11) {
        const float* pp = params + 15 * tid;
        float2 A1[2][2], B1[2][2], A2[2][2], B2[2][2];
        build_su2(pp + 0,  A1);
        build_su2(pp + 3,  B1);
        build_su2(pp + 9,  A2);
        build_su2(pp + 12, B2);
        float thx = pp[6], thy = pp[7], thz = pp[8];
        float Sa, Ca, Sb, Cb, sz, cz;
        sincosf(0.5f * (thx - thy), &Sa, &Ca);
        sincosf(0.5f * (thx + thy), &Sb, &Cb);
        sincosf(0.5f * thz, &sz, &cz);
        float2 pz  = make_float2(cz, -sz);
        float2 pzc = make_float2(cz,  sz);
        float2 K00 = make_float2(Ca * pz.x,  Ca * pz.y);
        float2 K03 = cmul(make_float2(0.f, -Sa), pz);
        float2 K11 = make_float2(Cb * pzc.x, Cb * pzc.y);
        float2 K12 = cmul(make_float2(0.f, -Sb), pzc);

        float2 T0[4][4], M1[4][4], G[4][4];
        #pragma unroll
        for (int i = 0; i < 2; ++i)
            #pragma unroll
            for (int jj = 0; jj < 2; ++jj)
                #pragma unroll
                for (int k = 0; k < 2; ++k)
                    #pragma unroll
                    for (int l = 0; l < 2; ++l) {
                        T0[2*i+jj][2*k+l] = cmul(A1[i][k], B1[jj][l]);
                        G [2*i+jj][2*k+l] = cmul(A2[i][k], B2[jj][l]);
                    }
        #pragma unroll
        for (int c = 0; c < 4; ++c) {
            M1[0][c] = cadd(cmul(K00, T0[0][c]), cmul(K03, T0[3][c]));
            M1[1][c] = cadd(cmul(K11, T0[1][c]), cmul(K12, T0[2][c]));
            M1[2][c] = cadd(cmul(K12, T0[1][c]), cmul(K11, T0[2][c]));
            M1[3][c] = cadd(cmul(K03, T0[0][c]), cmul(K00, T0[3][c]));
        }
        #pragma unroll
        for (int r = 0; r < 4; ++r)
            #pragma unroll
            for (int c = 0; c < 4; ++c) {
                float2 a = make_float2(0.f, 0.f);
                #pragma unroll
                for (int k = 0; k < 4; ++k) a = cfma2(G[r][k], M1[k][c], a);
                v4 o; o.x = a.x; o.y = a.x; o.z = a.y; o.w = a.y;
                gm[tid * 16 + r * 4 + c] = o;
            }
    } else if (tid == 11) {
        float2 F[2][2];
        build_su2(params + 165, F);
        #pragma unroll
        for (int k = 0; k < 4; ++k) {
            float2 a = F[k >> 1][k & 1];
            v4 o; o.x = a.x; o.y = a.x; o.z = a.y; o.w = a.y;
            gm[176 + k] = o;
        }
    }
}

// ---------- packed helpers ----------
// RY on register-array bit BIT (cp indices), state SoA: xr/xi v2 arrays of 16
template<int BIT>
__device__ __forceinline__ void ryg(v2* xr, v2* xi, float c, float s) {
    v2 cc; cc.x = c; cc.y = c;
    v2 ss; ss.x = s; ss.y = s;
    v2 ms; ms.x = -s; ms.y = -s;
    #pragma unroll
    for (int p = 0; p < 16; ++p) {
        if (p & (1 << BIT)) continue;
        const int q = p | (1 << BIT);
        v2 lr = xr[p], hr = xr[q], li = xi[p], hi = xi[q];
        xr[p] = pfma(ms, hr, cc * lr);
        xr[q] = pfma(ss, lr, cc * hr);
        xi[p] = pfma(ms, hi, cc * li);
        xi[q] = pfma(ss, li, cc * hi);
    }
}

// multiply amp-pair by per-half phase (C = re pair, S = im pair)
__device__ __forceinline__ void dmul(v2& r, v2& i, v4 L) {
    v2 C; C.x = L.x; C.y = L.y;
    v2 S; S.x = L.z; S.y = L.w;
    v2 nr = pfma(-S, i, C * r);
    v2 ni = pfma( S, r, C * i);
    r = nr; i = ni;
}

// 4x4 complex gate on cp bits (B1 = a-wire bit, B0 = b-wire bit); v = 2*b_a + b_b
template<int B1, int B0>
__device__ __forceinline__ void apply4(v2* xr, v2* xi, const v4* __restrict__ M) {
    #pragma unroll
    for (int f = 0; f < 16; ++f) {
        if (f & ((1 << B1) | (1 << B0))) continue;
        const int i1 = f | (1 << B0), i2 = f | (1 << B1), i3 = f | (1 << B1) | (1 << B0);
        v2 x0r = xr[f],  x1r = xr[i1], x2r = xr[i2], x3r = xr[i3];
        v2 x0i = xi[f],  x1i = xi[i1], x2i = xi[i2], x3i = xi[i3];
        v2 nr[4], ni[4];
        #pragma unroll
        for (int j = 0; j < 4; ++j) {
            v4 m0 = M[4*j], m1 = M[4*j+1], m2 = M[4*j+2], m3 = M[4*j+3];
            v2 c0, s0, c1, s1, c2, s2, c3, s3;
            c0.x = m0.x; c0.y = m0.y; s0.x = m0.z; s0.y = m0.w;
            c1.x = m1.x; c1.y = m1.y; s1.x = m1.z; s1.y = m1.w;
            c2.x = m2.x; c2.y = m2.y; s2.x = m2.z; s2.y = m2.w;
            c3.x = m3.x; c3.y = m3.y; s3.x = m3.z; s3.y = m3.w;
            v2 yr = c0 * x0r; yr = pfma(-s0, x0i, yr);
            v2 yi = c0 * x0i; yi = pfma( s0, x0r, yi);
            yr = pfma(c1, x1r, yr); yr = pfma(-s1, x1i, yr);
            yi = pfma(c1, x1i, yi); yi = pfma( s1, x1r, yi);
            yr = pfma(c2, x2r, yr); yr = pfma(-s2, x2i, yr);
            yi = pfma(c2, x2i, yi); yi = pfma( s2, x2r, yi);
            yr = pfma(c3, x3r, yr); yr = pfma(-s3, x3i, yr);
            yi = pfma(c3, x3i, yi); yi = pfma( s3, x3r, yi);
            nr[j] = yr; ni[j] = yi;
        }
        xr[f]  = nr[0]; xr[i1] = nr[1]; xr[i2] = nr[2]; xr[i3] = nr[3];
        xi[f]  = ni[0]; xi[i1] = ni[1]; xi[i2] = ni[2]; xi[i3] = ni[3];
    }
}

// ---------- main kernel ----------
__global__ __launch_bounds__(TPB, 2) void qcnn_main(
    const float* __restrict__ x,
    const float* __restrict__ W,
    const float* __restrict__ bias,
    const v4*    __restrict__ gm,
    float*       __restrict__ out)
{
    __shared__ __align__(16) v2 st[DIM];        // 32 KB state (canonical idx order, XOR-swizzled)
    __shared__ v4 lutA[16], lutB[16], lutC1[8], lutC2[4];
    __shared__ float2 L32s[32];
    __shared__ float sqf[NQ], sqc[NQ], sqs[NQ], zc[NQ-1], zs[NQ-1];
    __shared__ float redbuf[2];

    const int t = threadIdx.x;
    const int b = blockIdx.x;

    // stage 1: qfeat
    if (t < NQ) {
        float acc = bias[t];
        const float* xr_ = x + b * 16;
        const float* wr_ = W + t * 16;
        #pragma unroll
        for (int k = 0; k < 16; ++k) acc = fmaf(xr_[k], wr_[k], acc);
        sqf[t] = acc;
        float s, c;
        sincosf(0.5f * acc, &s, &c);
        sqc[t] = c; sqs[t] = s;
    }
    __syncthreads();
    // stage 2: ZZ half-angle tables
    if (t < NQ - 1) {
        float th = sqf[t] * sqf[t + 1];
        sincosf(0.5f * th, &zs[t], &zc[t]);
    }
    __syncthreads();
    // stage 3: LUTs.  P(q,a,b) = (zc[q], a==b ? -zs[q] : zs[q])
    if (t < 32) {
        int w = t;
        int bb[5];
        #pragma unroll
        for (int q = 0; q < 5; ++q) bb[q] = (w >> (4 - q)) & 1;
        float pr = 1.f;
        #pragma unroll
        for (int q = 0; q < 5; ++q) pr *= bb[q] ? sqs[q] : sqc[q];
        float2 ph = make_float2(1.f, 0.f);
        #pragma unroll
        for (int q = 0; q < 4; ++q) {
            float2 P = make_float2(zc[q], (bb[q] == bb[q+1]) ? -zs[q] : zs[q]);
            ph = cmul(ph, P);
        }
        L32s[w] = make_float2(pr * ph.x, pr * ph.y);
    } else if (t < 48) {      // lutA[g]: g = (b1,b2,b3,b4), halves = b0; D01,D12,D23,D34
        int g = t - 32;
        int b1 = (g >> 3) & 1, b2 = (g >> 2) & 1, b3 = (g >> 1) & 1, b4 = g & 1;
        float2 com = make_float2(zc[1], (b1 == b2) ? -zs[1] : zs[1]);
        com = cmul(com, make_float2(zc[2], (b2 == b3) ? -zs[2] : zs[2]));
        com = cmul(com, make_float2(zc[3], (b3 == b4) ? -zs[3] : zs[3]));
        float2 p0 = cmul(make_float2(zc[0], (0 == b1) ? -zs[0] : zs[0]), com);
        float2 p1 = cmul(make_float2(zc[0], (1 == b1) ? -zs[0] : zs[0]), com);
        v4 o; o.x = p0.x; o.y = p1.x; o.z = p0.y; o.w = p1.y;
        lutA[g] = o;
    } else if (t < 64) {      // lutB[g]: g = (b5,b6,b7,b8), halves = b4; D45,D56,D67,D78
        int g = t - 48;
        int b5 = (g >> 3) & 1, b6 = (g >> 2) & 1, b7 = (g >> 1) & 1, b8 = g & 1;
        float2 com = make_float2(zc[5], (b5 == b6) ? -zs[5] : zs[5]);
        com = cmul(com, make_float2(zc[6], (b6 == b7) ? -zs[6] : zs[6]));
        com = cmul(com, make_float2(zc[7], (b7 == b8) ? -zs[7] : zs[7]));
        float2 p0 = cmul(make_float2(zc[4], (0 == b5) ? -zs[4] : zs[4]), com);
        float2 p1 = cmul(make_float2(zc[4], (1 == b5) ? -zs[4] : zs[4]), com);
        v4 o; o.x = p0.x; o.y = p1.x; o.z = p0.y; o.w = p1.y;
        lutB[g] = o;
    } else if (t < 72) {      // lutC1[j]: j = (b8,b9,b10); D89, D9_10 (splat)
        int j = t - 64;
        int b8 = (j >> 2) & 1, b9 = (j >> 1) & 1, b10 = j & 1;
        float2 p = make_float2(zc[8], (b8 == b9) ? -zs[8] : zs[8]);
        p = cmul(p, make_float2(zc[9], (b9 == b10) ? -zs[9] : zs[9]));
        v4 o; o.x = p.x; o.y = p.x; o.z = p.y; o.w = p.y;
        lutC1[j] = o;
    } else if (t < 76) {      // lutC2[j]: j = (b10,b11); D10_11 (splat)
        int j = t - 72;
        int b10 = (j >> 1) & 1, b11 = j & 1;
        float2 p = make_float2(zc[10], (b10 == b11) ? -zs[10] : zs[10]);
        v4 o; o.x = p.x; o.y = p.x; o.z = p.y; o.w = p.y;
        lutC2[j] = o;
    }
    __syncthreads();

    const int tkA = t ^ (((t >> 5) & 3) << 1);

    // ================= PASS A: bits{11..7}=wires0..4. init + RY0-4 + diag(D01..D34) ====
    {
        const int b5 = (t >> 6) & 1, b6 = (t >> 5) & 1, b7 = (t >> 4) & 1, b8 = (t >> 3) & 1;
        const int b9 = (t >> 2) & 1, b10 = (t >> 1) & 1, b11 = t & 1;
        float prod = (b5 ? sqs[5] : sqc[5]) * (b6 ? sqs[6] : sqc[6]) * (b7 ? sqs[7] : sqc[7])
                   * (b8 ? sqs[8] : sqc[8]) * (b9 ? sqs[9] : sqc[9]) * (b10 ? sqs[10] : sqc[10])
                   * (b11 ? sqs[11] : sqc[11]);
        int tb[7] = { b5, b6, b7, b8, b9, b10, b11 };
        float2 ph = make_float2(1.f, 0.f);
        #pragma unroll
        for (int j = 0; j < 6; ++j) {
            int q = 5 + j;
            ph = cmul(ph, make_float2(zc[q], (tb[j] == tb[j+1]) ? -zs[q] : zs[q]));
        }
        float2 base = make_float2(prod * ph.x, prod * ph.y);
        float2 pre0 = cmul(base, make_float2(zc[4], (0 == b5) ? -zs[4] : zs[4]));
        float2 pre1 = cmul(base, make_float2(zc[4], (1 == b5) ? -zs[4] : zs[4]));

        v2 xr[16], xi[16];          // pair = w0 (wire4), cp = w4w3w2w1
        #pragma unroll
        for (int cp = 0; cp < 16; ++cp) {
            float2 a0 = cmul(L32s[cp << 1], pre0);
            float2 a1 = cmul(L32s[(cp << 1) | 1], pre1);
            v2 r; r.x = a0.x; r.y = a1.x; xr[cp] = r;
            v2 i; i.x = a0.y; i.y = a1.y; xi[cp] = i;
        }
        ryg<3>(xr, xi, sqc[0], sqs[0]);     // RY0 (wire0 = cp bit3)
        ryg<2>(xr, xi, sqc[1], sqs[1]);
        ryg<1>(xr, xi, sqc[2], sqs[2]);
        ryg<0>(xr, xi, sqc[3], sqs[3]);
        // repack pair w0 -> w4: ncp = w3w2w1w0
        v2 yr[16], yi[16];
        #pragma unroll
        for (int n = 0; n < 16; ++n) {
            int a = n >> 1, bq = 8 | (n >> 1);
            yr[n] = (n & 1) ? __builtin_shufflevector(xr[a], xr[bq], 1, 3)
                            : __builtin_shufflevector(xr[a], xr[bq], 0, 2);
            yi[n] = (n & 1) ? __builtin_shufflevector(xi[a], xi[bq], 1, 3)
                            : __builtin_shufflevector(xi[a], xi[bq], 0, 2);
        }
        ryg<0>(yr, yi, sqc[4], sqs[4]);     // RY4 (wire4 = ncp bit0)
        #pragma unroll
        for (int n = 0; n < 16; ++n) dmul(yr[n], yi[n], lutA[n]);
        // store pair=w4: idx = h<<11 | n<<7 | t
        #pragma unroll
        for (int n = 0; n < 16; ++n) {
            #pragma unroll
            for (int h = 0; h < 2; ++h) {
                const int C = ((h << 11) | (n << 7)) ^ ((n & 1) << 3) ^ (((n >> 1) & 7) << 1);
                v2 val;
                val.x = h ? yr[n].y : yr[n].x;
                val.y = h ? yi[n].y : yi[n].x;
                st[tkA ^ C] = val;
            }
        }
    }
    __syncthreads();

    // ================= PASS B': bits{7..3}=wires4..8. RY5-8 + diag(D45..D78) + E45,E67,E56
    {
        const int tH = t >> 3, tL = t & 7;
        const int tkB = ((tH << 8) | tL) ^ ((tH & 7) << 1);
        v2 xr[16], xi[16];          // pair = w4 (wire4), cp = w3w2w1w0 (wires 5,6,7,8)
        #pragma unroll
        for (int cp = 0; cp < 16; ++cp) {
            const int C0 = (cp << 3) ^ (((cp >> 2) & 3) << 1);
            const int C1 = ((1 << 7) | (cp << 3)) ^ ((((1 << 2) | (cp >> 2)) & 7) << 1);
            v2 a0 = st[tkB ^ C0];
            v2 a1 = st[tkB ^ C1];
            v2 r; r.x = a0.x; r.y = a1.x; xr[cp] = r;
            v2 i; i.x = a0.y; i.y = a1.y; xi[cp] = i;
        }
        ryg<3>(xr, xi, sqc[5], sqs[5]);
        ryg<2>(xr, xi, sqc[6], sqs[6]);
        ryg<1>(xr, xi, sqc[7], sqs[7]);
        ryg<0>(xr, xi, sqc[8], sqs[8]);
        #pragma unroll
        for (int cp = 0; cp < 16; ++cp) dmul(xr[cp], xi[cp], lutB[cp]);
        // repack pair w4 -> w0: cp' = w4w3w2w1
        v2 yr[16], yi[16];
        #pragma unroll
        for (int n = 0; n < 16; ++n) {
            int a = (n & 7) << 1, bq = a | 1;
            yr[n] = (n >> 3) ? __builtin_shufflevector(xr[a], xr[bq], 1, 3)
                             : __builtin_shufflevector(xr[a], xr[bq], 0, 2);
            yi[n] = (n >> 3) ? __builtin_shufflevector(xi[a], xi[bq], 1, 3)
                             : __builtin_shufflevector(xi[a], xi[bq], 0, 2);
        }
        apply4<3, 2>(yr, yi, gm + 2 * 16);   // E45 (wire4=cp'3, wire5=cp'2)
        apply4<1, 0>(yr, yi, gm + 3 * 16);   // E67
        apply4<2, 1>(yr, yi, gm + 8 * 16);   // E56 (odd)
        // store pair=w0: idx = tH<<8 | cp'<<4 | h<<3 | tL
        #pragma unroll
        for (int n = 0; n < 16; ++n) {
            #pragma unroll
            for (int h = 0; h < 2; ++h) {
                const int C = ((n << 4) | (h << 3)) ^ (((n >> 1) & 7) << 1);
                v2 val;
                val.x = h ? yr[n].y : yr[n].x;
                val.y = h ? yi[n].y : yi[n].x;
                st[tkB ^ C] = val;
            }
        }
    }
    __syncthreads();

    // ============ PASS C'': bits{4..0}=wires7..11. RY9-11 + diag(D89..D10_11) + E89,E10_11,E9_10,E78
    {
        const int kc = ((t & 7) ^ ((t >> 3) & 7)) & 7;
        const int tkC = (t << 5) ^ (kc << 1);
        v2 xr[16], xi[16];          // pair = w0 (wire11), cp = w4w3w2w1 (wires 7,8,9,10)
        #pragma unroll
        for (int cp = 0; cp < 16; ++cp) {
            v4 q = *(const v4*)(st + (tkC ^ (cp << 1)));
            v2 r; r.x = q.x; r.y = q.z; xr[cp] = r;
            v2 i; i.x = q.y; i.y = q.w; xi[cp] = i;
        }
        ryg<1>(xr, xi, sqc[9],  sqs[9]);    // RY9 (wire9 = cp bit1)
        ryg<0>(xr, xi, sqc[10], sqs[10]);   // RY10
        #pragma unroll
        for (int cp = 0; cp < 16; ++cp) dmul(xr[cp], xi[cp], lutC1[cp & 7]);
        // repack pair w0 -> w4: ncp = w3w2w1w0 (wires 8,9,10,11)
        v2 yr[16], yi[16];
        #pragma unroll
        for (int n = 0; n < 16; ++n) {
            int a = n >> 1, bq = 8 | (n >> 1);
            yr[n] = (n & 1) ? __builtin_shufflevector(xr[a], xr[bq], 1, 3)
                            : __builtin_shufflevector(xr[a], xr[bq], 0, 2);
            yi[n] = (n & 1) ? __builtin_shufflevector(xi[a], xi[bq], 1, 3)
                            : __builtin_shufflevector(xi[a], xi[bq], 0, 2);
        }
        ryg<0>(yr, yi, sqc[11], sqs[11]);   // RY11
        #pragma unroll
        for (int n = 0; n < 16; ++n) dmul(yr[n], yi[n], lutC2[n & 3]);
        apply4<3, 2>(yr, yi, gm + 4 * 16);   // E89
        apply4<1, 0>(yr, yi, gm + 5 * 16);   // E10_11
        apply4<2, 1>(yr, yi, gm + 10 * 16);  // E9_10 (odd)
        // repack pair w4 -> w0: cp = w4w3w2w1
        v2 zr[16], zi[16];
        #pragma unroll
        for (int n = 0; n < 16; ++n) {
            int a = (n & 7) << 1, bq = a | 1;
            zr[n] = (n >> 3) ? __builtin_shufflevector(yr[a], yr[bq], 1, 3)
                             : __builtin_shufflevector(yr[a], yr[bq], 0, 2);
            zi[n] = (n >> 3) ? __builtin_shufflevector(yi[a], yi[bq], 1, 3)
                             : __builtin_shufflevector(yi[a], yi[bq], 0, 2);
        }
        apply4<3, 2>(zr, zi, gm + 9 * 16);   // E78 (wire7=cp3, wire8=cp2)
        // store pair=w0 (b128)
        #pragma unroll
        for (int cp = 0; cp < 16; ++cp) {
            v4 q;
            q.x = zr[cp].x; q.y = zi[cp].x; q.z = zr[cp].y; q.w = zi[cp].y;
            *(v4*)(st + (tkC ^ (cp << 1))) = q;
        }
    }
    __syncthreads();

    // ================= PASS D: bits{11..7}. E01,E23,E12,E34 + F(wire0) + reduce ========
    {
        v2 xr[16], xi[16];          // pair = w0 (wire4), cp = w4w3w2w1 (wires 0,1,2,3)
        #pragma unroll
        for (int cp = 0; cp < 16; ++cp) {
            const int C0 = (cp << 8) ^ ((cp & 7) << 1);
            const int C1 = ((cp << 8) | (1 << 7)) ^ (1 << 3) ^ ((cp & 7) << 1);
            v2 a0 = st[tkA ^ C0];
            v2 a1 = st[tkA ^ C1];
            v2 r; r.x = a0.x; r.y = a1.x; xr[cp] = r;
            v2 i; i.x = a0.y; i.y = a1.y; xi[cp] = i;
        }
        apply4<3, 2>(xr, xi, gm + 0 * 16);   // E01
        apply4<1, 0>(xr, xi, gm + 1 * 16);   // E23
        apply4<2, 1>(xr, xi, gm + 6 * 16);   // E12 (odd)
        // repack pair w0 -> w2: ncp = w4w3w1w0
        v2 yr[16], yi[16];
        #pragma unroll
        for (int n = 0; n < 16; ++n) {
            int a = (n & 0xC) | ((n >> 1) & 1), bq = a | 2;
            yr[n] = (n & 1) ? __builtin_shufflevector(xr[a], xr[bq], 1, 3)
                            : __builtin_shufflevector(xr[a], xr[bq], 0, 2);
            yi[n] = (n & 1) ? __builtin_shufflevector(xi[a], xi[bq], 1, 3)
                            : __builtin_shufflevector(xi[a], xi[bq], 0, 2);
        }
        apply4<1, 0>(yr, yi, gm + 7 * 16);   // E34 (wire3=ncp1, wire4=ncp0)
        // final SU2 on wire0 (ncp bit3) fused with |.|^2 reduce
        v4 f00 = gm[176], f01 = gm[177], f10 = gm[178], f11 = gm[179];
        v2 C00, S00, C01, S01, C10, S10, C11, S11;
        C00.x = f00.x; C00.y = f00.y; S00.x = f00.z; S00.y = f00.w;
        C01.x = f01.x; C01.y = f01.y; S01.x = f01.z; S01.y = f01.w;
        C10.x = f10.x; C10.y = f10.y; S10.x = f10.z; S10.y = f10.w;
        C11.x = f11.x; C11.y = f11.y; S11.x = f11.z; S11.y = f11.w;
        v2 accP; accP.x = 0.f; accP.y = 0.f;
        v2 accN; accN.x = 0.f; accN.y = 0.f;
        #pragma unroll
        for (int lo = 0; lo < 8; ++lo) {
            const int hi = lo | 8;
            v2 ar = yr[lo], ai = yi[lo], br = yr[hi], bi = yi[hi];
            v2 pr = C00 * ar; pr = pfma(-S00, ai, pr); pr = pfma(C01, br, pr); pr = pfma(-S01, bi, pr);
            v2 pi = C00 * ai; pi = pfma( S00, ar, pi); pi = pfma(C01, bi, pi); pi = pfma( S01, br, pi);
            v2 qr = C10 * ar; qr = pfma(-S10, ai, qr); qr = pfma(C11, br, qr); qr = pfma(-S11, bi, qr);
            v2 qi = C10 * ai; qi = pfma( S10, ar, qi); qi = pfma(C11, bi, qi); qi = pfma( S11, br, qi);
            accP = pfma(pr, pr, accP); accP = pfma(pi, pi, accP);
            accN = pfma(qr, qr, accN); accN = pfma(qi, qi, accN);
        }
        float d = (accP.x + accP.y) - (accN.x + accN.y);
        #pragma unroll
        for (int off = 32; off > 0; off >>= 1) d += __shfl_down(d, off);
        if ((t & 63) == 0) redbuf[t >> 6] = d;
        __syncthreads();
        if (t == 0) {
            float dd = redbuf[0] + redbuf[1];
            float y = 0.5f * (dd + 1.0f);
            y = fminf(fmaxf(y, 1e-6f), 1.0f - 1e-6f);
            out[b] = y;
        }
    }
}

extern "C" void kernel_launch(void* const* d_in, const int* in_sizes, int n_in,
                              void* d_out, int out_size, void* d_ws, size_t ws_size,
                              hipStream_t stream) {
    (void)in_sizes; (void)n_in; (void)ws_size;
    const float* x      = (const float*)d_in[0];
    const float* W      = (const float*)d_in[1];
    const float* bias   = (const float*)d_in[2];
    const float* params = (const float*)d_in[3];
    float* out = (float*)d_out;
    v4* gm = (v4*)d_ws;
    hipLaunchKernelGGL(qcnn_setup, dim3(1), dim3(64), 0, stream, params, gm);
    hipLaunchKernelGGL(qcnn_main, dim3(out_size), dim3(TPB), 0, stream,
                       x, W, bias, (const v4*)gm, out);
}

// Round 4
// 13.232 us; speedup vs baseline: 16.1746x; 7.6120x over previous
//
#include <hip/hip_runtime.h>
#include <math.h>

__device__ __forceinline__ float2 cmul(float2 a, float2 b) {
    return make_float2(a.x*b.x - a.y*b.y, a.x*b.y + a.y*b.x);
}
__device__ __forceinline__ float2 cadd(float2 a, float2 b) {
    return make_float2(a.x + b.x, a.y + b.y);
}
__device__ __forceinline__ float2 cfma2(float2 a, float2 b, float2 c) {
    c.x = fmaf(a.x, b.x, fmaf(-a.y, b.y, c.x));
    c.y = fmaf(a.x, b.y, fmaf( a.y, b.x, c.y));
    return c;
}

// U = Rz(p2) @ Ry(p1) @ Rz(p0)
__device__ __forceinline__ void build_su2(const float* __restrict__ p, float2 U[2][2]) {
    float sb, cb;
    sincosf(0.5f * p[1], &sb, &cb);
    float ap = 0.5f * (p[0] + p[2]);
    float am = 0.5f * (p[0] - p[2]);
    float sap, cap, sam, cam;
    sincosf(ap, &sap, &cap);
    sincosf(am, &sam, &cam);
    U[0][0] = make_float2( cb * cap, -cb * sap);
    U[0][1] = make_float2(-sb * cam, -sb * sam);
    U[1][0] = make_float2( sb * cam, -sb * sam);
    U[1][1] = make_float2( cb * cap,  cb * sap);
}

// ---- one-time setup: compose E01 (full 15-param block on wires 0,1) and
//      M = F^dagger Z F (measurement operator after final SU2 on wire 0) ----
// g[0..31]  : E01 4x4 complex row-major (re,im)
// g[32]     : M00 (real)   g[33]: M11 (real)   g[34],g[35]: Re/Im M01
__global__ void qcnn_setup(const float* __restrict__ params, float* __restrict__ g) {
    if (threadIdx.x != 0 || blockIdx.x != 0) return;
    const float* pp = params;           // block (0,1) = first 15 params
    float2 A1[2][2], B1[2][2], A2[2][2], B2[2][2];
    build_su2(pp + 0,  A1);
    build_su2(pp + 3,  B1);
    build_su2(pp + 9,  A2);
    build_su2(pp + 12, B2);
    float thx = pp[6], thy = pp[7], thz = pp[8];
    float Sa, Ca, Sb, Cb, sz, cz;
    sincosf(0.5f * (thx - thy), &Sa, &Ca);   // {00,11} subspace
    sincosf(0.5f * (thx + thy), &Sb, &Cb);   // {01,10} subspace
    sincosf(0.5f * thz, &sz, &cz);
    float2 pz  = make_float2(cz, -sz);
    float2 pzc = make_float2(cz,  sz);
    float2 K00 = make_float2(Ca * pz.x,  Ca * pz.y);
    float2 K03 = cmul(make_float2(0.f, -Sa), pz);
    float2 K11 = make_float2(Cb * pzc.x, Cb * pzc.y);
    float2 K12 = cmul(make_float2(0.f, -Sb), pzc);

    float2 T0[4][4], M1[4][4], T2[4][4];
    #pragma unroll
    for (int i = 0; i < 2; ++i)
        #pragma unroll
        for (int jj = 0; jj < 2; ++jj)
            #pragma unroll
            for (int k = 0; k < 2; ++k)
                #pragma unroll
                for (int l = 0; l < 2; ++l) {
                    T0[2*i+jj][2*k+l] = cmul(A1[i][k], B1[jj][l]);
                    T2[2*i+jj][2*k+l] = cmul(A2[i][k], B2[jj][l]);
                }
    #pragma unroll
    for (int c = 0; c < 4; ++c) {
        M1[0][c] = cadd(cmul(K00, T0[0][c]), cmul(K03, T0[3][c]));
        M1[1][c] = cadd(cmul(K11, T0[1][c]), cmul(K12, T0[2][c]));
        M1[2][c] = cadd(cmul(K12, T0[1][c]), cmul(K11, T0[2][c]));
        M1[3][c] = cadd(cmul(K03, T0[0][c]), cmul(K00, T0[3][c]));
    }
    #pragma unroll
    for (int r = 0; r < 4; ++r)
        #pragma unroll
        for (int c = 0; c < 4; ++c) {
            float2 a = make_float2(0.f, 0.f);
            #pragma unroll
            for (int k = 0; k < 4; ++k) a = cfma2(T2[r][k], M1[k][c], a);
            g[2*(4*r+c)]     = a.x;
            g[2*(4*r+c) + 1] = a.y;
        }

    float2 F[2][2];
    build_su2(params + 165, F);         // final SU2 on wire 0
    float n00 = F[0][0].x*F[0][0].x + F[0][0].y*F[0][0].y;
    float n10 = F[1][0].x*F[1][0].x + F[1][0].y*F[1][0].y;
    float n01 = F[0][1].x*F[0][1].x + F[0][1].y*F[0][1].y;
    float n11 = F[1][1].x*F[1][1].x + F[1][1].y*F[1][1].y;
    g[32] = n00 - n10;                  // M00
    g[33] = n01 - n11;                  // M11
    // M01 = conj(F00)*F01 - conj(F10)*F11
    float mr = (F[0][0].x*F[0][1].x + F[0][0].y*F[0][1].y)
             - (F[1][0].x*F[1][1].x + F[1][0].y*F[1][1].y);
    float mi = (F[0][0].x*F[0][1].y - F[0][0].y*F[0][1].x)
             - (F[1][0].x*F[1][1].y - F[1][0].y*F[1][1].x);
    g[34] = mr;
    g[35] = mi;
}

// ---- main kernel: one thread per batch element; 4-qubit (16-amp) circuit ----
// wire w <-> bit (3-w) of the amp index (wire0 = bit3, ..., wire3 = bit0)
__global__ __launch_bounds__(64) void qcnn_main(
    const float* __restrict__ x,
    const float* __restrict__ W,
    const float* __restrict__ bias,
    const float* __restrict__ g,
    float* __restrict__ out,
    int n)
{
    const int tid = blockIdx.x * 64 + threadIdx.x;
    if (tid >= n) return;

    // E01 and M are grid-uniform -> scalar loads into SGPRs
    float2 E[16];
    #pragma unroll
    for (int e = 0; e < 16; ++e) E[e] = make_float2(g[2*e], g[2*e+1]);
    const float m00 = g[32], m11 = g[33], mr = g[34], mi = g[35];

    // qfeat for wires 0..3 only
    const float* xr = x + tid * 16;
    float xv[16];
    #pragma unroll
    for (int k = 0; k < 16; ++k) xv[k] = xr[k];
    float qf[4];
    #pragma unroll
    for (int q = 0; q < 4; ++q) {
        const float* wr = W + q * 16;
        float acc = bias[q];
        #pragma unroll
        for (int k = 0; k < 16; ++k) acc = fmaf(xv[k], wr[k], acc);
        qf[q] = acc;
    }
    float c[4], s[4];
    #pragma unroll
    for (int q = 0; q < 4; ++q) sincosf(0.5f * qf[q], &s[q], &c[q]);
    float zs01, zc01, zs12, zc12, zs23, zc23;
    sincosf(0.5f * qf[0] * qf[1], &zs01, &zc01);
    sincosf(0.5f * qf[1] * qf[2], &zs12, &zc12);
    sincosf(0.5f * qf[2] * qf[3], &zs23, &zc23);
    // ZZ pair factor: equal bits -> e^{-i z/2} = (zc, -zs); differing -> (zc, +zs)
    const float2 f01e = make_float2(zc01, -zs01), f01d = make_float2(zc01, zs01);
    const float2 f12e = make_float2(zc12, -zs12), f12d = make_float2(zc12, zs12);
    const float2 f23e = make_float2(zc23, -zs23), f23d = make_float2(zc23, zs23);

    // init: L1 product state (RY0-3 on |0000>) * L1 ZZ phases (01),(12),(23)
    float ar[16], ai[16];
    #pragma unroll
    for (int i = 0; i < 16; ++i) {
        const int b0 = (i >> 3) & 1, b1 = (i >> 2) & 1, b2 = (i >> 1) & 1, b3 = i & 1;
        float mag = (b0 ? s[0] : c[0]) * (b1 ? s[1] : c[1])
                  * (b2 ? s[2] : c[2]) * (b3 ? s[3] : c[3]);
        float2 ph = cmul(cmul(b0 == b1 ? f01e : f01d,
                              b1 == b2 ? f12e : f12d),
                         b2 == b3 ? f23e : f23d);
        ar[i] = mag * ph.x;
        ai[i] = mag * ph.y;
    }

    // L2: RY(qf0) on bit3, RY(qf1) on bit2, RY(qf2) on bit1   (RY3 is dead)
    #pragma unroll
    for (int p = 0; p < 16; ++p) if (!(p & 8)) {
        const int q = p | 8;
        float lr = ar[p], li = ai[p], hr = ar[q], hi = ai[q];
        ar[p] = fmaf(c[0], lr, -s[0] * hr);  ai[p] = fmaf(c[0], li, -s[0] * hi);
        ar[q] = fmaf(s[0], lr,  c[0] * hr);  ai[q] = fmaf(s[0], li,  c[0] * hi);
    }
    #pragma unroll
    for (int p = 0; p < 16; ++p) if (!(p & 4)) {
        const int q = p | 4;
        float lr = ar[p], li = ai[p], hr = ar[q], hi = ai[q];
        ar[p] = fmaf(c[1], lr, -s[1] * hr);  ai[p] = fmaf(c[1], li, -s[1] * hi);
        ar[q] = fmaf(s[1], lr,  c[1] * hr);  ai[q] = fmaf(s[1], li,  c[1] * hi);
    }
    #pragma unroll
    for (int p = 0; p < 16; ++p) if (!(p & 2)) {
        const int q = p | 2;
        float lr = ar[p], li = ai[p], hr = ar[q], hi = ai[q];
        ar[p] = fmaf(c[2], lr, -s[2] * hr);  ai[p] = fmaf(c[2], li, -s[2] * hi);
        ar[q] = fmaf(s[2], lr,  c[2] * hr);  ai[q] = fmaf(s[2], li,  c[2] * hi);
    }

    // L2 ZZ phases: (0,1) on bits (3,2); (1,2) on bits (2,1)   [(2,3) is dead]
    #pragma unroll
    for (int i = 0; i < 16; ++i) {
        const int b0 = (i >> 3) & 1, b1 = (i >> 2) & 1, b2 = (i >> 1) & 1;
        float2 gp = cmul(b0 == b1 ? f01e : f01d, b1 == b2 ? f12e : f12d);
        float nr = ar[i] * gp.x - ai[i] * gp.y;
        float ni = ar[i] * gp.y + ai[i] * gp.x;
        ar[i] = nr; ai[i] = ni;
    }

    // E01: 4x4 complex on v = 2*bit3 + bit2; groups = (bit1,bit0)
    #pragma unroll
    for (int gq = 0; gq < 4; ++gq) {
        float xrv[4], xiv[4];
        #pragma unroll
        for (int v = 0; v < 4; ++v) { xrv[v] = ar[(v << 2) | gq]; xiv[v] = ai[(v << 2) | gq]; }
        #pragma unroll
        for (int r = 0; r < 4; ++r) {
            float yr = 0.f, yi = 0.f;
            #pragma unroll
            for (int v = 0; v < 4; ++v) {
                const float2 m = E[r * 4 + v];
                yr = fmaf(m.x, xrv[v], fmaf(-m.y, xiv[v], yr));
                yi = fmaf(m.x, xiv[v], fmaf( m.y, xrv[v], yi));
            }
            ar[(r << 2) | gq] = yr;
            ai[(r << 2) | gq] = yi;
        }
    }

    // measurement: d = <psi| M_0 |psi>,  M = F^dag Z F on wire0 (bit3)
    float d = 0.f;
    #pragma unroll
    for (int i = 0; i < 8; ++i) {
        const float lr = ar[i], li = ai[i], hr = ar[i + 8], hi = ai[i + 8];
        float cross = mr * (lr * hr + li * hi) - mi * (lr * hi - li * hr);
        d += m00 * (lr * lr + li * li) + m11 * (hr * hr + hi * hi) + 2.f * cross;
    }
    float y = 0.5f * (d + 1.0f);
    out[tid] = fminf(fmaxf(y, 1e-6f), 1.0f - 1e-6f);
}

extern "C" void kernel_launch(void* const* d_in, const int* in_sizes, int n_in,
                              void* d_out, int out_size, void* d_ws, size_t ws_size,
                              hipStream_t stream) {
    (void)in_sizes; (void)n_in; (void)ws_size;
    const float* x      = (const float*)d_in[0];
    const float* W      = (const float*)d_in[1];
    const float* bias   = (const float*)d_in[2];
    const float* params = (const float*)d_in[3];
    float* out = (float*)d_out;
    float* g = (float*)d_ws;
    hipLaunchKernelGGL(qcnn_setup, dim3(1), dim3(64), 0, stream, params, g);
    hipLaunchKernelGGL(qcnn_main, dim3((out_size + 63) / 64), dim3(64), 0, stream,
                       x, W, bias, (const float*)g, out, out_size);
}